// Round 2
// baseline (270.319 us; speedup 1.0000x reference)
//
#include <hip/hip_runtime.h>
#include <hip/hip_bf16.h>

// Problem constants (LearnedQueryAttention): B=8, L=4096, KD=512, ED=1024, H=8
// All inputs/outputs are fp32 (reference dtypes). NaN failure in round 1 was
// diagnostic: reading fp32 bits as bf16 pairs produces Inf/NaN decodes.
#define BATCH 8
#define LSEQ  4096
#define LP    4097        // L+1 (appended bias token)
#define KDIM  512
#define EDIM  1024
#define NH    8
#define DK    64          // KD/H
#define DV    128         // ED/H
#define NG    (BATCH*NH)  // 64 (b,h) groups
#define SSTR  4112        // padded per-group score row stride (floats)
#define NC    16          // value chunks per group
#define RC    257         // rows per chunk (16*257 = 4112 >= 4097)
#define LN_EPS 1e-5f

// ---------------------------------------------------------------------------
// Raw-reshape semantics: concat([X, bias], axis=1).reshape(B*H, L+1, C/H) means
// head h owns the contiguous flat slab f = h*(L+1)*(C/H) + row*(C/H) + d of the
// per-batch [X_flat | bias] buffer. Only f >= L*C touches the bias token.
// ---------------------------------------------------------------------------

// Kernel 1: raw scores s[g][row] = dot64(Q[h], Kcat[b][f..f+63]).
// Grid (8 row-chunks, 64 groups); 16 lanes per row, float4 per lane.
__global__ __launch_bounds__(256) void scores_kernel(
    const float* __restrict__ keys, const float* __restrict__ k_bias,
    const float* __restrict__ query, float* __restrict__ p)
{
    const int chunk = blockIdx.x;            // 0..7
    const int g = blockIdx.y;                // 0..63
    const int b = g >> 3, h = g & 7;
    const int t = threadIdx.x;
    const int lane16 = t & 15;
    const int d0 = lane16 * 4;

    const float4 q = *reinterpret_cast<const float4*>(query + h * DK + d0);

    const float* kp = keys + (long long)b * (LSEQ * KDIM);
    const int fhead = h * (LP * DK);
    const int row0 = chunk * 513;
    const int row_end = min(LP, row0 + 513);
    float* prow = p + (long long)g * SSTR;

    for (int row = row0 + (t >> 4); row < row_end; row += 16) {
        const int f = fhead + row * DK + d0;
        const float4 k = (f < LSEQ * KDIM)
                       ? *reinterpret_cast<const float4*>(kp + f)
                       : *reinterpret_cast<const float4*>(k_bias + (f - LSEQ * KDIM));
        float s = q.x * k.x + q.y * k.y + q.z * k.z + q.w * k.w;
        s += __shfl_xor(s, 1);
        s += __shfl_xor(s, 2);
        s += __shfl_xor(s, 4);
        s += __shfl_xor(s, 8);
        if (lane16 == 0) prow[row] = s;
    }
}

// Kernel 2: per group g: t = s*w + b; overwrite score row with exp(t - max);
// Z[g] = sum of exps. One block per g.
__global__ __launch_bounds__(256) void softmax_kernel(
    const float* __restrict__ sw, const float* __restrict__ sb,
    float* __restrict__ p, float* __restrict__ Z)
{
    const int g = blockIdx.x;
    const int h = g & 7;
    const int t = threadIdx.x;
    float* prow = p + (long long)g * SSTR;
    const float* w = sw + h * LP;
    const float* bb = sb + h * LP;
    __shared__ float red[256];

    float m = -1e30f;
    for (int j = t; j < LP; j += 256)
        m = fmaxf(m, prow[j] * w[j] + bb[j]);
    red[t] = m; __syncthreads();
    for (int off = 128; off > 0; off >>= 1) {
        if (t < off) red[t] = fmaxf(red[t], red[t + off]);
        __syncthreads();
    }
    m = red[0];
    __syncthreads();

    float z = 0.f;
    for (int j = t; j < LP; j += 256) {
        float e = __expf(prow[j] * w[j] + bb[j] - m);
        prow[j] = e;
        z += e;
    }
    red[t] = z; __syncthreads();
    for (int off = 128; off > 0; off >>= 1) {
        if (t < off) red[t] += red[t + off];
        __syncthreads();
    }
    if (t == 0) Z[g] = red[0];
}

// Kernel 3: A_partial[g][chunk][d] = sum_{rows in chunk} p[row] * Vcat[f].
// 32 lanes per row (float4), 8 row subsets in flight, LDS tree-reduce.
// Grid (16 chunks, 64 groups).
__global__ __launch_bounds__(256) void av_kernel(
    const float* __restrict__ values, const float* __restrict__ v_bias,
    const float* __restrict__ p, float* __restrict__ partials)
{
    const int chunk = blockIdx.x;            // 0..15
    const int g = blockIdx.y;                // 0..63
    const int b = g >> 3, h = g & 7;
    const int t = threadIdx.x;
    const int srow = t >> 5;                 // 0..7: row subset
    const int d0 = (t & 31) * 4;             // 0..124

    const float* vp = values + (long long)b * (LSEQ * EDIM);
    const int fhead = h * (LP * DV);
    const float* prow = p + (long long)g * SSTR;
    const int row0 = chunk * RC;
    const int row_end = min(LP, row0 + RC);

    float acc[4] = {0.f, 0.f, 0.f, 0.f};
    for (int row = row0 + srow; row < row_end; row += 8) {
        const float pw = prow[row];
        const int f = fhead + row * DV + d0;
        const float4 v = (f < LSEQ * EDIM)
                       ? *reinterpret_cast<const float4*>(vp + f)
                       : *reinterpret_cast<const float4*>(v_bias + (f - LSEQ * EDIM));
        acc[0] += pw * v.x; acc[1] += pw * v.y;
        acc[2] += pw * v.z; acc[3] += pw * v.w;
    }

    __shared__ float red[256 * 4];
#pragma unroll
    for (int j = 0; j < 4; ++j) red[t * 4 + j] = acc[j];
    for (int off = 128; off >= 32; off >>= 1) {
        __syncthreads();
        if (t < off) {
#pragma unroll
            for (int j = 0; j < 4; ++j) red[t * 4 + j] += red[(t + off) * 4 + j];
        }
    }
    __syncthreads();
    if (t < 32) {
        float* dst = partials + ((long long)(g * NC + chunk)) * DV + t * 4;
#pragma unroll
        for (int j = 0; j < 4; ++j) dst[j] = red[t * 4 + j];
    }
}

// Kernel 4: reduce chunk partials, divide by per-head Z, LayerNorm over 1024
// embed dims (biased var, eps 1e-5), apply gamma/beta. One block per batch.
__global__ __launch_bounds__(256) void ln_kernel(
    const float* __restrict__ partials, const float* __restrict__ Z,
    const float* __restrict__ gamma, const float* __restrict__ beta,
    float* __restrict__ out)
{
    const int b = blockIdx.x;
    const int t = threadIdx.x;
    __shared__ float r1[256], r2[256];

    float a[4];
    float s1 = 0.f, s2 = 0.f;
#pragma unroll
    for (int i = 0; i < 4; ++i) {
        const int e = t + i * 256;
        const int h = e >> 7, d = e & 127;
        const float* src = partials + ((long long)((b * NH + h) * NC)) * DV + d;
        float sum = 0.f;
#pragma unroll
        for (int c = 0; c < NC; ++c) sum += src[c * DV];
        const float av = sum / Z[b * NH + h];
        a[i] = av;
        s1 += av;
        s2 += av * av;
    }
    r1[t] = s1; r2[t] = s2; __syncthreads();
    for (int off = 128; off > 0; off >>= 1) {
        if (t < off) { r1[t] += r1[t + off]; r2[t] += r2[t + off]; }
        __syncthreads();
    }
    const float mean = r1[0] * (1.0f / EDIM);
    const float var = r2[0] * (1.0f / EDIM) - mean * mean;
    const float inv = rsqrtf(var + LN_EPS);
#pragma unroll
    for (int i = 0; i < 4; ++i) {
        const int e = t + i * 256;
        out[(long long)b * EDIM + e] =
            (a[i] - mean) * inv * gamma[e] + beta[e];
    }
}

// ---------------------------------------------------------------------------
extern "C" void kernel_launch(void* const* d_in, const int* in_sizes, int n_in,
                              void* d_out, int out_size, void* d_ws, size_t ws_size,
                              hipStream_t stream) {
    const float* keys   = (const float*)d_in[0];
    const float* values = (const float*)d_in[1];
    const float* query  = (const float*)d_in[2];
    const float* k_bias = (const float*)d_in[3];
    const float* v_bias = (const float*)d_in[4];
    const float* sw     = (const float*)d_in[5];
    const float* sb     = (const float*)d_in[6];
    const float* gamma  = (const float*)d_in[7];
    const float* beta   = (const float*)d_in[8];
    float* out = (float*)d_out;

    // ws layout (floats): p[NG][SSTR] | Z[NG] | partials[NG][NC][DV]  (~1.6 MB)
    float* ws = (float*)d_ws;
    float* p = ws;
    float* Z = ws + (long long)NG * SSTR;
    float* partials = Z + NG;

    scores_kernel <<<dim3(8, NG),  256, 0, stream>>>(keys, k_bias, query, p);
    softmax_kernel<<<NG,           256, 0, stream>>>(sw, sb, p, Z);
    av_kernel     <<<dim3(NC, NG), 256, 0, stream>>>(values, v_bias, p, partials);
    ln_kernel     <<<BATCH,        256, 0, stream>>>(partials, Z, gamma, beta, out);
}